// Round 15
// baseline (102.792 us; speedup 1.0000x reference)
//
#include <hip/hip_runtime.h>
#include <hip/hip_bf16.h>

typedef unsigned short u16;
typedef __bf16 bf16x8 __attribute__((ext_vector_type(8)));
typedef float  f32x4  __attribute__((ext_vector_type(4)));

#define BB    4
#define SS    4096
#define DD    1024
#define EE    8
#define M_TOT (BB*SS)   /* 16384 */
#define N_TOT DD        /* 1024  */
#define K_TOT DD        /* 1024  */

#define BK 64
#define NT (K_TOT/BK)   /* 16 K-tiles */

#define GATE_BLOCKS 1024   /* 16 tokens per block, 4 per wave */
#define GEMM_BLOCKS ((M_TOT/128)*(N_TOT/128))  /* 1024 worst-case */
#define ZTOK 32
#define ZBLOCKS (M_TOT/ZTOK)                    /* 512 zero-role blocks */

__device__ __forceinline__ u16 f2bf(float f) {
  unsigned u = __builtin_bit_cast(unsigned, f);
  u += 0x7fffu + ((u >> 16) & 1u);          // round-to-nearest-even
  return (u16)(u >> 16);
}

__device__ __forceinline__ void stage16(u16* lds, const u16* g) {
  __builtin_amdgcn_global_load_lds((const __attribute__((address_space(1))) void*)g,
                                   (__attribute__((address_space(3))) void*)lds,
                                   16, 0, 0);
}

// ---------------------------------------------------------------------------
// Kernel 1: gate (fp32, exact) + token f32->bf16 convert + weight convert +
// active-list build.  LEAN hot loop (r14 lesson: conditional zero-row stores
// inside the token loop serialized the load pipeline, 19->66 us).  Zero rows
// are now written by zero-role blocks inside kernel 2.
// ---------------------------------------------------------------------------
__global__ __launch_bounds__(256) void gate_convert_kernel(
    const float* __restrict__ tokens, const float* __restrict__ gate_w,
    const float* __restrict__ w0,     const float* __restrict__ w1,
    u16* __restrict__ tok_bf, u16* __restrict__ w0_bf, u16* __restrict__ w1_bf,
    float* __restrict__ scales, int* __restrict__ counter,
    int* __restrict__ list)
{
  const int bid = blockIdx.x;
  const int tid = threadIdx.x;

  if (bid < GATE_BLOCKS) {
    __shared__ float gwT[EE][DD];       // 32 KB, transposed gate weights
    #pragma unroll
    for (int r = 0; r < 4; ++r) {
      const int d = r * 256 + tid;      // coalesced: lanes 32B apart
      float4 a = *(const float4*)&gate_w[d * EE];
      float4 b = *(const float4*)&gate_w[d * EE + 4];
      gwT[0][d] = a.x; gwT[1][d] = a.y; gwT[2][d] = a.z; gwT[3][d] = a.w;
      gwT[4][d] = b.x; gwT[5][d] = b.y; gwT[6][d] = b.z; gwT[7][d] = b.w;
    }
    __syncthreads();

    const int lane = tid & 63, wid = tid >> 6;
    const int tbase = (bid * 4 + wid) * 4;          // 4 tokens per wave

    float lg[4][EE];
    #pragma unroll
    for (int t = 0; t < 4; ++t)
      #pragma unroll
      for (int e = 0; e < EE; ++e) lg[t][e] = 0.0f;

    #pragma unroll
    for (int c = 0; c < 4; ++c) {
      const int d = c * 256 + lane * 4;
      float4 gw[EE];
      #pragma unroll
      for (int e = 0; e < EE; ++e)
        gw[e] = *(const float4*)&gwT[e][d];         // ds_read_b128, lanes 16B apart
      #pragma unroll
      for (int t = 0; t < 4; ++t) {
        const size_t off = (size_t)(tbase + t) * DD + d;
        float4 v = *(const float4*)(tokens + off);
        *(ushort4*)(tok_bf + off) =
            make_ushort4(f2bf(v.x), f2bf(v.y), f2bf(v.z), f2bf(v.w));
        #pragma unroll
        for (int e = 0; e < EE; ++e)
          lg[t][e] = fmaf(v.w, gw[e].w, fmaf(v.z, gw[e].z,
                     fmaf(v.y, gw[e].y, fmaf(v.x, gw[e].x, lg[t][e]))));
      }
    }

    // Expert-splitting butterfly reduce, then shuffle softmax/top-2.
    const int b0 = lane & 1, b1 = (lane >> 1) & 1, b2 = (lane >> 2) & 1;
    const int E  = b0 * 4 + (lane & 2) + b2;

    #pragma unroll
    for (int t = 0; t < 4; ++t) {
      float n0[4], n1[2], rr;
      #pragma unroll
      for (int i = 0; i < 4; ++i) {
        float send = b0 ? lg[t][i] : lg[t][i + 4];
        float keep = b0 ? lg[t][i + 4] : lg[t][i];
        n0[i] = keep + __shfl_xor(send, 1, 64);
      }
      #pragma unroll
      for (int i = 0; i < 2; ++i) {
        float send = b1 ? n0[i] : n0[i + 2];
        float keep = b1 ? n0[i + 2] : n0[i];
        n1[i] = keep + __shfl_xor(send, 2, 64);
      }
      {
        float send = b2 ? n1[0] : n1[1];
        float keep = b2 ? n1[1] : n1[0];
        rr = keep + __shfl_xor(send, 4, 64);
      }
      rr += __shfl_xor(rr, 8, 64);
      rr += __shfl_xor(rr, 16, 64);
      rr += __shfl_xor(rr, 32, 64);

      float m = rr;
      m = fmaxf(m, __shfl_xor(m, 1, 64));
      m = fmaxf(m, __shfl_xor(m, 2, 64));
      m = fmaxf(m, __shfl_xor(m, 4, 64));
      float p = __expf(rr - m);
      float s = p;
      s += __shfl_xor(s, 1, 64);
      s += __shfl_xor(s, 2, 64);
      s += __shfl_xor(s, 4, 64);

      int cnt = 0;
      #pragma unroll
      for (int k = 1; k < 8; ++k) {
        float Lo = __shfl_xor(rr, k, 64);
        const int Eo = E ^ ((k & 1) * 4 + (k & 2) + ((k >> 2) & 1));
        cnt += (Lo > rr || (Lo == rr && Eo < E)) ? 1 : 0;
      }
      if (lane < 8) {
        const float w = p / s;
        if (E == 0) scales[(tbase + t) * 2 + 0] = (cnt == 0) ? w : 0.0f;
        if (E == 1) scales[(tbase + t) * 2 + 1] = (cnt == 1) ? w : 0.0f;
      }
      // Active-list build (E(lane0)=0, E(lane4)=1).
      const bool myact = (lane == 0 && cnt == 0) || (lane == 4 && cnt == 1);
      const unsigned long long bal = __ballot(myact ? 1 : 0);
      if (bal != 0ULL && lane == 0) {
        const int pos = atomicAdd(counter, 1);
        list[pos] = tbase + t;
      }
    }
  } else {
    const int wb = bid - GATE_BLOCKS;            // 0..2047
    const float* src = (wb < 1024) ? w0 : w1;
    u16*        dst = (wb < 1024) ? w0_bf : w1_bf;
    const int base = (wb & 1023) * 1024 + tid * 4;
    float4 v = *(const float4*)(src + base);
    *(ushort4*)(dst + base) =
        make_ushort4(f2bf(v.x), f2bf(v.y), f2bf(v.z), f2bf(v.w));
  }
}

// ---------------------------------------------------------------------------
// Kernel 2: SPARSE fused dual-GEMM over the active-token list (~23% of rows)
// + zero-role blocks (bid >= 1024) that stream zero rows for inactive tokens
// (s0==0 && s1==0 — exact complement of the list; underflow edge case means
// both paths may write the same row, but both write identical 0.0 -> benign).
// GEMM structure unchanged from r14 (verified): BM=128 x BN=128, gathered
// A-staging via per-lane global_load_lds source, swizzled LDS, SGB pins,
// scatter epilogue.
// ---------------------------------------------------------------------------
__global__ __launch_bounds__(256, 1) void moe_gemm_sparse(
    const u16* __restrict__ A,    // [M,K] bf16 (token-major)
    const u16* __restrict__ Bw0,  // [N,K] bf16
    const u16* __restrict__ Bw1,  // [N,K] bf16
    const float* __restrict__ bias0, const float* __restrict__ bias1,
    const float* __restrict__ scales, // [M,2]
    const int* __restrict__ list, const int* __restrict__ counter,
    float* __restrict__ out)      // [M,N] f32
{
  const int bid = blockIdx.x;
  const int tid = threadIdx.x;

  if (bid >= GEMM_BLOCKS) {
    // ---- zero-role block: 32 tokens, write 4KB zero row if inactive ----
    const int t0 = (bid - GEMM_BLOCKS) * ZTOK;
    const float4 z = make_float4(0.f, 0.f, 0.f, 0.f);
    for (int t = 0; t < ZTOK; ++t) {
      const int tok = t0 + t;
      if (scales[tok * 2] == 0.0f && scales[tok * 2 + 1] == 0.0f)
        *(float4*)(out + (size_t)tok * DD + tid * 4) = z;
    }
    return;
  }

  const int n_active = *counter;
  const int bm = bid >> 3, bn = bid & 7;
  const int m0 = bm * 128, n0 = bn * 128;
  if (m0 >= n_active) return;

  __shared__ u16 lA [2][128 * BK];   // 32 KiB
  __shared__ u16 lB0[2][128 * BK];   // 32 KiB
  __shared__ u16 lB1[2][128 * BK];   // 32 KiB -> 96 KiB

  const int lane = tid & 63;
  const int wid  = tid >> 6;                  // 0..3
  const int wm = wid >> 1, wn = wid & 1;      // 2M x 2N wave grid
  const int fr = lane & 15, fq = lane >> 4;
  const int frh = fr >> 1;                    // read-swizzle term

  // staging: thread covers rows {tid>>3 + 32c}, phys chunk tid&7.
  const int schunk = ((tid & 7) ^ ((tid >> 4) & 7)) * 8;
  const u16* gAr[4];
  #pragma unroll
  for (int c = 0; c < 4; ++c) {
    int m = m0 + (tid >> 3) + 32 * c;
    if (m >= n_active) m = n_active - 1;      // pad: duplicate last row
    gAr[c] = A + (size_t)list[m] * K_TOT + schunk;
  }
  const u16* gB0 = Bw0 + (size_t)(n0 + (tid >> 3)) * K_TOT + schunk;
  const u16* gB1 = Bw1 + (size_t)(n0 + (tid >> 3)) * K_TOT + schunk;

#define STAGE_A(buf, c, ko)  stage16(&lA [buf][(c)*2048 + tid*8], gAr[c] + (ko))
#define STAGE_B0(buf, c, ko) stage16(&lB0[buf][(c)*2048 + tid*8], gB0 + (size_t)(c)*32*K_TOT + (ko))
#define STAGE_B1(buf, c, ko) stage16(&lB1[buf][(c)*2048 + tid*8], gB1 + (size_t)(c)*32*K_TOT + (ko))

#define FRAG(L, buf, rowbase, kk) \
  (*(const bf16x8*)&L[buf][((rowbase) + fr) * BK + ((((kk) << 2) | fq) ^ frh) * 8])

#define BAR()        __builtin_amdgcn_s_barrier()
#define WAIT_VM(N)   asm volatile("s_waitcnt vmcnt(" #N ")" ::: "memory")
#define SGB(m, n)    __builtin_amdgcn_sched_group_barrier((m), (n), 0)

#define MFMA16(ACC, AF, BF) do {                                              \
    __builtin_amdgcn_s_setprio(1);                                            \
    _Pragma("unroll")                                                         \
    for (int i = 0; i < 4; ++i)                                               \
      _Pragma("unroll")                                                       \
      for (int j = 0; j < 4; ++j)                                             \
        ACC[i][j] = __builtin_amdgcn_mfma_f32_16x16x32_bf16(AF[i], BF[j],     \
                                                            ACC[i][j], 0,0,0);\
    __builtin_amdgcn_s_setprio(0);                                            \
  } while (0)

#define STAGE_ALL(buf, ko) do {                                               \
    STAGE_A(buf, 0, ko);  STAGE_A(buf, 1, ko);                                \
    STAGE_A(buf, 2, ko);  STAGE_A(buf, 3, ko);                                \
    STAGE_B0(buf, 0, ko); STAGE_B0(buf, 1, ko);                               \
    STAGE_B0(buf, 2, ko); STAGE_B0(buf, 3, ko);                               \
    STAGE_B1(buf, 0, ko); STAGE_B1(buf, 1, ko);                               \
    STAGE_B1(buf, 2, ko); STAGE_B1(buf, 3, ko);                               \
  } while (0)

  f32x4 acc0[4][4] = {};
  f32x4 acc1[4][4] = {};
  bf16x8 afA[4], afB[4], b0A[4], b0B[4], b1A[4], b1B[4];

  // Prologue: stage K-tile 0, drain, barrier.
  STAGE_ALL(0, 0);
  WAIT_VM(0);
  BAR();

  int cur = 0;
  for (int t = 0; t < NT - 1; ++t) {
    const int nxt = cur ^ 1;
    const size_t ko = (size_t)(t + 1) * BK;

    // reads: q1(afA,b0A) q2(afB,b0B) q3(b1A,b1B)
    #pragma unroll
    for (int i = 0; i < 4; ++i) afA[i] = FRAG(lA,  cur, wm * 64 + i * 16, 0);
    #pragma unroll
    for (int j = 0; j < 4; ++j) b0A[j] = FRAG(lB0, cur, wn * 64 + j * 16, 0);
    #pragma unroll
    for (int i = 0; i < 4; ++i) afB[i] = FRAG(lA,  cur, wm * 64 + i * 16, 1);
    #pragma unroll
    for (int j = 0; j < 4; ++j) b0B[j] = FRAG(lB0, cur, wn * 64 + j * 16, 1);
    #pragma unroll
    for (int j = 0; j < 4; ++j) b1A[j] = FRAG(lB1, cur, wn * 64 + j * 16, 0);
    #pragma unroll
    for (int j = 0; j < 4; ++j) b1B[j] = FRAG(lB1, cur, wn * 64 + j * 16, 1);
    STAGE_ALL(nxt, ko);

    MFMA16(acc0, afA, b0A);
    MFMA16(acc0, afB, b0B);
    MFMA16(acc1, afA, b1A);
    MFMA16(acc1, afB, b1B);

    // interleave pins: batch1 after q1; stages+q2/q3 drain under batches.
    SGB(0x100, 8);  SGB(0x008, 16);
    SGB(0x100, 8);  SGB(0x010, 4);  SGB(0x008, 16);
    SGB(0x100, 8);  SGB(0x010, 8);  SGB(0x008, 16);
    SGB(0x008, 16);

    WAIT_VM(0);
    BAR();
    cur = nxt;
  }

  // Peeled last tile (no prefetch).
  {
    #pragma unroll
    for (int i = 0; i < 4; ++i) afA[i] = FRAG(lA,  cur, wm * 64 + i * 16, 0);
    #pragma unroll
    for (int j = 0; j < 4; ++j) b0A[j] = FRAG(lB0, cur, wn * 64 + j * 16, 0);
    #pragma unroll
    for (int i = 0; i < 4; ++i) afB[i] = FRAG(lA,  cur, wm * 64 + i * 16, 1);
    #pragma unroll
    for (int j = 0; j < 4; ++j) b0B[j] = FRAG(lB0, cur, wn * 64 + j * 16, 1);
    #pragma unroll
    for (int j = 0; j < 4; ++j) b1A[j] = FRAG(lB1, cur, wn * 64 + j * 16, 0);
    #pragma unroll
    for (int j = 0; j < 4; ++j) b1B[j] = FRAG(lB1, cur, wn * 64 + j * 16, 1);
    MFMA16(acc0, afA, b0A);
    MFMA16(acc0, afB, b0B);
    MFMA16(acc1, afA, b1A);
    MFMA16(acc1, afB, b1B);
  }

  // Epilogue: scatter out[list[m]] = s0*silu(acc0+b0) + s1*silu(acc1+b1)
  float bb0[4], bb1[4];
  #pragma unroll
  for (int j = 0; j < 4; ++j) {
    const int col = n0 + wn * 64 + j * 16 + fr;
    bb0[j] = bias0[col];
    bb1[j] = bias1[col];
  }
  #pragma unroll
  for (int i = 0; i < 4; ++i) {
    #pragma unroll
    for (int r = 0; r < 4; ++r) {
      const int m = m0 + wm * 64 + i * 16 + fq * 4 + r;  // C row=(lane>>4)*4+reg
      if (m < n_active) {
        const int gidx = list[m];
        const float s0 = scales[gidx * 2 + 0];
        const float s1 = scales[gidx * 2 + 1];
        float* orow = out + (size_t)gidx * N_TOT + n0 + wn * 64;
        #pragma unroll
        for (int j = 0; j < 4; ++j) {
          const float v0 = acc0[i][j][r] + bb0[j];
          const float v1 = acc1[i][j][r] + bb1[j];
          const float g0 = v0 / (1.0f + __expf(-v0));
          const float g1 = v1 / (1.0f + __expf(-v1));
          orow[j * 16 + fr] = s0 * g0 + s1 * g1;           // col = lane&15
        }
      }
    }
  }
#undef STAGE_A
#undef STAGE_B0
#undef STAGE_B1
#undef STAGE_ALL
#undef FRAG
#undef BAR
#undef WAIT_VM
#undef SGB
#undef MFMA16
}

// ---------------------------------------------------------------------------
extern "C" void kernel_launch(void* const* d_in, const int* in_sizes, int n_in,
                              void* d_out, int out_size, void* d_ws, size_t ws_size,
                              hipStream_t stream)
{
  const float* tokens = (const float*)d_in[0];
  const float* gate_w = (const float*)d_in[1];
  const float* w0     = (const float*)d_in[2];
  const float* b0     = (const float*)d_in[3];
  const float* w1     = (const float*)d_in[4];
  const float* b1     = (const float*)d_in[5];
  float* out = (float*)d_out;

  char* ws = (char*)d_ws;
  const size_t off_w0  = (size_t)M_TOT * K_TOT * 2;            // 32 MB
  const size_t off_w1  = off_w0 + (size_t)N_TOT * K_TOT * 2;   // +2 MB
  const size_t off_sc  = off_w1 + (size_t)N_TOT * K_TOT * 2;   // +2 MB
  const size_t off_cnt = off_sc + (size_t)M_TOT * 2 * 4;       // +128 KB
  const size_t off_lst = off_cnt + 256;

  u16* tok_bf   = (u16*)ws;
  u16* w0_bf    = (u16*)(ws + off_w0);
  u16* w1_bf    = (u16*)(ws + off_w1);
  float* scales = (float*)(ws + off_sc);
  int* counter  = (int*)(ws + off_cnt);
  int* list     = (int*)(ws + off_lst);

  hipMemsetAsync(counter, 0, sizeof(int), stream);

  gate_convert_kernel<<<GATE_BLOCKS + 2048, 256, 0, stream>>>(
      tokens, gate_w, w0, w1, tok_bf, w0_bf, w1_bf, scales, counter, list);

  moe_gemm_sparse<<<GEMM_BLOCKS + ZBLOCKS, 256, 0, stream>>>(
      tok_bf, w0_bf, w1_bf, b0, b1, scales, list, counter, out);
}

// Round 16
// 69.569 us; speedup vs baseline: 1.4776x; 1.4776x over previous
//
#include <hip/hip_runtime.h>
#include <hip/hip_bf16.h>

typedef unsigned short u16;
typedef __bf16 bf16x8 __attribute__((ext_vector_type(8)));
typedef float  f32x4  __attribute__((ext_vector_type(4)));

#define BB    4
#define SS    4096
#define DD    1024
#define EE    8
#define M_TOT (BB*SS)   /* 16384 */
#define N_TOT DD        /* 1024  */
#define K_TOT DD        /* 1024  */

#define BK 64
#define NT (K_TOT/BK)   /* 16 K-tiles */

#define GATE_BLOCKS 1024   /* 16 tokens per block, 4 per wave */
#define GEMM_BLOCKS ((M_TOT/128)*(N_TOT/128))  /* 1024 worst-case */
#define ZTOK 32
#define ZBLOCKS (M_TOT/ZTOK)                    /* 512 zero-role blocks */

__device__ __forceinline__ u16 f2bf(float f) {
  unsigned u = __builtin_bit_cast(unsigned, f);
  u += 0x7fffu + ((u >> 16) & 1u);          // round-to-nearest-even
  return (u16)(u >> 16);
}

__device__ __forceinline__ void stage16(u16* lds, const u16* g) {
  __builtin_amdgcn_global_load_lds((const __attribute__((address_space(1))) void*)g,
                                   (__attribute__((address_space(3))) void*)lds,
                                   16, 0, 0);
}

// ---------------------------------------------------------------------------
// Kernel 1: gate (fp32, exact) + token f32->bf16 convert + weight convert.
// NO ATOMICS (r15 lesson: ~3800 same-address device-scope atomicAdds cost
// ~40 us — fabric-coherence serialization).  Activity is written as a
// per-token flag; a 1-block scan kernel builds the dense sorted list.
// ---------------------------------------------------------------------------
__global__ __launch_bounds__(256) void gate_convert_kernel(
    const float* __restrict__ tokens, const float* __restrict__ gate_w,
    const float* __restrict__ w0,     const float* __restrict__ w1,
    u16* __restrict__ tok_bf, u16* __restrict__ w0_bf, u16* __restrict__ w1_bf,
    float* __restrict__ scales, int* __restrict__ flags)
{
  const int bid = blockIdx.x;
  const int tid = threadIdx.x;

  if (bid < GATE_BLOCKS) {
    __shared__ float gwT[EE][DD];       // 32 KB, transposed gate weights
    #pragma unroll
    for (int r = 0; r < 4; ++r) {
      const int d = r * 256 + tid;      // coalesced: lanes 32B apart
      float4 a = *(const float4*)&gate_w[d * EE];
      float4 b = *(const float4*)&gate_w[d * EE + 4];
      gwT[0][d] = a.x; gwT[1][d] = a.y; gwT[2][d] = a.z; gwT[3][d] = a.w;
      gwT[4][d] = b.x; gwT[5][d] = b.y; gwT[6][d] = b.z; gwT[7][d] = b.w;
    }
    __syncthreads();

    const int lane = tid & 63, wid = tid >> 6;
    const int tbase = (bid * 4 + wid) * 4;          // 4 tokens per wave

    float lg[4][EE];
    #pragma unroll
    for (int t = 0; t < 4; ++t)
      #pragma unroll
      for (int e = 0; e < EE; ++e) lg[t][e] = 0.0f;

    #pragma unroll
    for (int c = 0; c < 4; ++c) {
      const int d = c * 256 + lane * 4;
      float4 gw[EE];
      #pragma unroll
      for (int e = 0; e < EE; ++e)
        gw[e] = *(const float4*)&gwT[e][d];         // ds_read_b128, lanes 16B apart
      #pragma unroll
      for (int t = 0; t < 4; ++t) {
        const size_t off = (size_t)(tbase + t) * DD + d;
        float4 v = *(const float4*)(tokens + off);
        *(ushort4*)(tok_bf + off) =
            make_ushort4(f2bf(v.x), f2bf(v.y), f2bf(v.z), f2bf(v.w));
        #pragma unroll
        for (int e = 0; e < EE; ++e)
          lg[t][e] = fmaf(v.w, gw[e].w, fmaf(v.z, gw[e].z,
                     fmaf(v.y, gw[e].y, fmaf(v.x, gw[e].x, lg[t][e]))));
      }
    }

    // Expert-splitting butterfly reduce, then shuffle softmax/top-2.
    const int b0 = lane & 1, b1 = (lane >> 1) & 1, b2 = (lane >> 2) & 1;
    const int E  = b0 * 4 + (lane & 2) + b2;

    #pragma unroll
    for (int t = 0; t < 4; ++t) {
      float n0[4], n1[2], rr;
      #pragma unroll
      for (int i = 0; i < 4; ++i) {
        float send = b0 ? lg[t][i] : lg[t][i + 4];
        float keep = b0 ? lg[t][i + 4] : lg[t][i];
        n0[i] = keep + __shfl_xor(send, 1, 64);
      }
      #pragma unroll
      for (int i = 0; i < 2; ++i) {
        float send = b1 ? n0[i] : n0[i + 2];
        float keep = b1 ? n0[i + 2] : n0[i];
        n1[i] = keep + __shfl_xor(send, 2, 64);
      }
      {
        float send = b2 ? n1[0] : n1[1];
        float keep = b2 ? n1[1] : n1[0];
        rr = keep + __shfl_xor(send, 4, 64);
      }
      rr += __shfl_xor(rr, 8, 64);
      rr += __shfl_xor(rr, 16, 64);
      rr += __shfl_xor(rr, 32, 64);

      float m = rr;
      m = fmaxf(m, __shfl_xor(m, 1, 64));
      m = fmaxf(m, __shfl_xor(m, 2, 64));
      m = fmaxf(m, __shfl_xor(m, 4, 64));
      float p = __expf(rr - m);
      float s = p;
      s += __shfl_xor(s, 1, 64);
      s += __shfl_xor(s, 2, 64);
      s += __shfl_xor(s, 4, 64);

      int cnt = 0;
      #pragma unroll
      for (int k = 1; k < 8; ++k) {
        float Lo = __shfl_xor(rr, k, 64);
        const int Eo = E ^ ((k & 1) * 4 + (k & 2) + ((k >> 2) & 1));
        cnt += (Lo > rr || (Lo == rr && Eo < E)) ? 1 : 0;
      }
      // lane 4 holds E==1: grab its (cnt==1) predicate.
      const int act1 = __shfl(((E == 1) && (cnt == 1)) ? 1 : 0, 4, 64);
      if (lane < 8) {
        const float w = p / s;
        if (E == 0) scales[(tbase + t) * 2 + 0] = (cnt == 0) ? w : 0.0f;
        if (E == 1) scales[(tbase + t) * 2 + 1] = (cnt == 1) ? w : 0.0f;
      }
      if (lane == 0)
        flags[tbase + t] = ((cnt == 0) ? 1 : 0) | act1;
    }
  } else {
    const int wb = bid - GATE_BLOCKS;            // 0..2047
    const float* src = (wb < 1024) ? w0 : w1;
    u16*        dst = (wb < 1024) ? w0_bf : w1_bf;
    const int base = (wb & 1023) * 1024 + tid * 4;
    float4 v = *(const float4*)(src + base);
    *(ushort4*)(dst + base) =
        make_ushort4(f2bf(v.x), f2bf(v.y), f2bf(v.z), f2bf(v.w));
  }
}

// ---------------------------------------------------------------------------
// Kernel 1.5: single-block prefix-scan list build (deterministic, atomic-free,
// produces a SORTED dense active list + count).  1024 threads x 16 tokens.
// ---------------------------------------------------------------------------
__global__ __launch_bounds__(1024) void scan_kernel(
    const int* __restrict__ flags, int* __restrict__ list,
    int* __restrict__ counter)
{
  __shared__ int wsum[16];
  const int t = threadIdx.x;
  const int lane = t & 63, w = t >> 6;

  int f[16]; int cnt = 0;
  #pragma unroll
  for (int i = 0; i < 16; ++i) { f[i] = flags[t * 16 + i]; cnt += f[i]; }

  // inclusive scan across the wave
  int sc = cnt;
  #pragma unroll
  for (int off = 1; off < 64; off <<= 1) {
    const int v = __shfl_up(sc, off, 64);
    if (lane >= off) sc += v;
  }
  if (lane == 63) wsum[w] = sc;
  __syncthreads();

  if (w == 0) {              // scan the 16 wave totals in wave 0
    int v = (lane < 16) ? wsum[lane] : 0;
    #pragma unroll
    for (int off = 1; off < 16; off <<= 1) {
      const int u = __shfl_up(v, off, 64);
      if (lane >= off) v += u;
    }
    if (lane < 16) wsum[lane] = v;       // inclusive wave prefix
    if (lane == 15) *counter = v;        // total active
  }
  __syncthreads();

  const int wbase = (w == 0) ? 0 : wsum[w - 1];
  int run = wbase + (sc - cnt);          // exclusive prefix for this thread
  #pragma unroll
  for (int i = 0; i < 16; ++i)
    if (f[i]) list[run++] = t * 16 + i;
}

// ---------------------------------------------------------------------------
// Kernel 2: SPARSE fused dual-GEMM over the active-token list (~23% of rows)
// + zero-role blocks (bid >= 1024) streaming zero rows for inactive tokens
// (flags[tok]==0).  GEMM structure unchanged (r14-verified): BM=128 x
// BN=128, gathered A-staging via per-lane global_load_lds source, swizzled
// LDS, SGB pins, scatter epilogue.  List is now sorted -> better locality.
// ---------------------------------------------------------------------------
__global__ __launch_bounds__(256, 1) void moe_gemm_sparse(
    const u16* __restrict__ A,    // [M,K] bf16 (token-major)
    const u16* __restrict__ Bw0,  // [N,K] bf16
    const u16* __restrict__ Bw1,  // [N,K] bf16
    const float* __restrict__ bias0, const float* __restrict__ bias1,
    const float* __restrict__ scales, // [M,2]
    const int* __restrict__ list, const int* __restrict__ counter,
    const int* __restrict__ flags,
    float* __restrict__ out)      // [M,N] f32
{
  const int bid = blockIdx.x;
  const int tid = threadIdx.x;

  if (bid >= GEMM_BLOCKS) {
    // ---- zero-role block: 32 tokens, write 4KB zero row if inactive ----
    const int t0 = (bid - GEMM_BLOCKS) * ZTOK;
    const float4 z = make_float4(0.f, 0.f, 0.f, 0.f);
    for (int t = 0; t < ZTOK; ++t) {
      const int tok = t0 + t;
      if (flags[tok] == 0)
        *(float4*)(out + (size_t)tok * DD + tid * 4) = z;
    }
    return;
  }

  const int n_active = *counter;
  const int bm = bid >> 3, bn = bid & 7;
  const int m0 = bm * 128, n0 = bn * 128;
  if (m0 >= n_active) return;

  __shared__ u16 lA [2][128 * BK];   // 32 KiB
  __shared__ u16 lB0[2][128 * BK];   // 32 KiB
  __shared__ u16 lB1[2][128 * BK];   // 32 KiB -> 96 KiB

  const int lane = tid & 63;
  const int wid  = tid >> 6;                  // 0..3
  const int wm = wid >> 1, wn = wid & 1;      // 2M x 2N wave grid
  const int fr = lane & 15, fq = lane >> 4;
  const int frh = fr >> 1;                    // read-swizzle term

  // staging: thread covers rows {tid>>3 + 32c}, phys chunk tid&7.
  const int schunk = ((tid & 7) ^ ((tid >> 4) & 7)) * 8;
  const u16* gAr[4];
  #pragma unroll
  for (int c = 0; c < 4; ++c) {
    int m = m0 + (tid >> 3) + 32 * c;
    if (m >= n_active) m = n_active - 1;      // pad: duplicate last row
    gAr[c] = A + (size_t)list[m] * K_TOT + schunk;
  }
  const u16* gB0 = Bw0 + (size_t)(n0 + (tid >> 3)) * K_TOT + schunk;
  const u16* gB1 = Bw1 + (size_t)(n0 + (tid >> 3)) * K_TOT + schunk;

#define STAGE_A(buf, c, ko)  stage16(&lA [buf][(c)*2048 + tid*8], gAr[c] + (ko))
#define STAGE_B0(buf, c, ko) stage16(&lB0[buf][(c)*2048 + tid*8], gB0 + (size_t)(c)*32*K_TOT + (ko))
#define STAGE_B1(buf, c, ko) stage16(&lB1[buf][(c)*2048 + tid*8], gB1 + (size_t)(c)*32*K_TOT + (ko))

#define FRAG(L, buf, rowbase, kk) \
  (*(const bf16x8*)&L[buf][((rowbase) + fr) * BK + ((((kk) << 2) | fq) ^ frh) * 8])

#define BAR()        __builtin_amdgcn_s_barrier()
#define WAIT_VM(N)   asm volatile("s_waitcnt vmcnt(" #N ")" ::: "memory")
#define SGB(m, n)    __builtin_amdgcn_sched_group_barrier((m), (n), 0)

#define MFMA16(ACC, AF, BF) do {                                              \
    __builtin_amdgcn_s_setprio(1);                                            \
    _Pragma("unroll")                                                         \
    for (int i = 0; i < 4; ++i)                                               \
      _Pragma("unroll")                                                       \
      for (int j = 0; j < 4; ++j)                                             \
        ACC[i][j] = __builtin_amdgcn_mfma_f32_16x16x32_bf16(AF[i], BF[j],     \
                                                            ACC[i][j], 0,0,0);\
    __builtin_amdgcn_s_setprio(0);                                            \
  } while (0)

#define STAGE_ALL(buf, ko) do {                                               \
    STAGE_A(buf, 0, ko);  STAGE_A(buf, 1, ko);                                \
    STAGE_A(buf, 2, ko);  STAGE_A(buf, 3, ko);                                \
    STAGE_B0(buf, 0, ko); STAGE_B0(buf, 1, ko);                               \
    STAGE_B0(buf, 2, ko); STAGE_B0(buf, 3, ko);                               \
    STAGE_B1(buf, 0, ko); STAGE_B1(buf, 1, ko);                               \
    STAGE_B1(buf, 2, ko); STAGE_B1(buf, 3, ko);                               \
  } while (0)

  f32x4 acc0[4][4] = {};
  f32x4 acc1[4][4] = {};
  bf16x8 afA[4], afB[4], b0A[4], b0B[4], b1A[4], b1B[4];

  // Prologue: stage K-tile 0, drain, barrier.
  STAGE_ALL(0, 0);
  WAIT_VM(0);
  BAR();

  int cur = 0;
  for (int t = 0; t < NT - 1; ++t) {
    const int nxt = cur ^ 1;
    const size_t ko = (size_t)(t + 1) * BK;

    // reads: q1(afA,b0A) q2(afB,b0B) q3(b1A,b1B)
    #pragma unroll
    for (int i = 0; i < 4; ++i) afA[i] = FRAG(lA,  cur, wm * 64 + i * 16, 0);
    #pragma unroll
    for (int j = 0; j < 4; ++j) b0A[j] = FRAG(lB0, cur, wn * 64 + j * 16, 0);
    #pragma unroll
    for (int i = 0; i < 4; ++i) afB[i] = FRAG(lA,  cur, wm * 64 + i * 16, 1);
    #pragma unroll
    for (int j = 0; j < 4; ++j) b0B[j] = FRAG(lB0, cur, wn * 64 + j * 16, 1);
    #pragma unroll
    for (int j = 0; j < 4; ++j) b1A[j] = FRAG(lB1, cur, wn * 64 + j * 16, 0);
    #pragma unroll
    for (int j = 0; j < 4; ++j) b1B[j] = FRAG(lB1, cur, wn * 64 + j * 16, 1);
    STAGE_ALL(nxt, ko);

    MFMA16(acc0, afA, b0A);
    MFMA16(acc0, afB, b0B);
    MFMA16(acc1, afA, b1A);
    MFMA16(acc1, afB, b1B);

    // interleave pins: batch1 after q1; stages+q2/q3 drain under batches.
    SGB(0x100, 8);  SGB(0x008, 16);
    SGB(0x100, 8);  SGB(0x010, 4);  SGB(0x008, 16);
    SGB(0x100, 8);  SGB(0x010, 8);  SGB(0x008, 16);
    SGB(0x008, 16);

    WAIT_VM(0);
    BAR();
    cur = nxt;
  }

  // Peeled last tile (no prefetch).
  {
    #pragma unroll
    for (int i = 0; i < 4; ++i) afA[i] = FRAG(lA,  cur, wm * 64 + i * 16, 0);
    #pragma unroll
    for (int j = 0; j < 4; ++j) b0A[j] = FRAG(lB0, cur, wn * 64 + j * 16, 0);
    #pragma unroll
    for (int i = 0; i < 4; ++i) afB[i] = FRAG(lA,  cur, wm * 64 + i * 16, 1);
    #pragma unroll
    for (int j = 0; j < 4; ++j) b0B[j] = FRAG(lB0, cur, wn * 64 + j * 16, 1);
    #pragma unroll
    for (int j = 0; j < 4; ++j) b1A[j] = FRAG(lB1, cur, wn * 64 + j * 16, 0);
    #pragma unroll
    for (int j = 0; j < 4; ++j) b1B[j] = FRAG(lB1, cur, wn * 64 + j * 16, 1);
    MFMA16(acc0, afA, b0A);
    MFMA16(acc0, afB, b0B);
    MFMA16(acc1, afA, b1A);
    MFMA16(acc1, afB, b1B);
  }

  // Epilogue: scatter out[list[m]] = s0*silu(acc0+b0) + s1*silu(acc1+b1)
  float bb0[4], bb1[4];
  #pragma unroll
  for (int j = 0; j < 4; ++j) {
    const int col = n0 + wn * 64 + j * 16 + fr;
    bb0[j] = bias0[col];
    bb1[j] = bias1[col];
  }
  #pragma unroll
  for (int i = 0; i < 4; ++i) {
    #pragma unroll
    for (int r = 0; r < 4; ++r) {
      const int m = m0 + wm * 64 + i * 16 + fq * 4 + r;  // C row=(lane>>4)*4+reg
      if (m < n_active) {
        const int gidx = list[m];
        const float s0 = scales[gidx * 2 + 0];
        const float s1 = scales[gidx * 2 + 1];
        float* orow = out + (size_t)gidx * N_TOT + n0 + wn * 64;
        #pragma unroll
        for (int j = 0; j < 4; ++j) {
          const float v0 = acc0[i][j][r] + bb0[j];
          const float v1 = acc1[i][j][r] + bb1[j];
          const float g0 = v0 / (1.0f + __expf(-v0));
          const float g1 = v1 / (1.0f + __expf(-v1));
          orow[j * 16 + fr] = s0 * g0 + s1 * g1;           // col = lane&15
        }
      }
    }
  }
#undef STAGE_A
#undef STAGE_B0
#undef STAGE_B1
#undef STAGE_ALL
#undef FRAG
#undef BAR
#undef WAIT_VM
#undef SGB
#undef MFMA16
}

// ---------------------------------------------------------------------------
extern "C" void kernel_launch(void* const* d_in, const int* in_sizes, int n_in,
                              void* d_out, int out_size, void* d_ws, size_t ws_size,
                              hipStream_t stream)
{
  const float* tokens = (const float*)d_in[0];
  const float* gate_w = (const float*)d_in[1];
  const float* w0     = (const float*)d_in[2];
  const float* b0     = (const float*)d_in[3];
  const float* w1     = (const float*)d_in[4];
  const float* b1     = (const float*)d_in[5];
  float* out = (float*)d_out;

  char* ws = (char*)d_ws;
  const size_t off_w0  = (size_t)M_TOT * K_TOT * 2;            // 32 MB
  const size_t off_w1  = off_w0 + (size_t)N_TOT * K_TOT * 2;   // +2 MB
  const size_t off_sc  = off_w1 + (size_t)N_TOT * K_TOT * 2;   // +2 MB
  const size_t off_cnt = off_sc + (size_t)M_TOT * 2 * 4;       // +128 KB
  const size_t off_lst = off_cnt + 256;
  const size_t off_flg = off_lst + (size_t)M_TOT * 4;          // +64 KB

  u16* tok_bf   = (u16*)ws;
  u16* w0_bf    = (u16*)(ws + off_w0);
  u16* w1_bf    = (u16*)(ws + off_w1);
  float* scales = (float*)(ws + off_sc);
  int* counter  = (int*)(ws + off_cnt);
  int* list     = (int*)(ws + off_lst);
  int* flags    = (int*)(ws + off_flg);

  gate_convert_kernel<<<GATE_BLOCKS + 2048, 256, 0, stream>>>(
      tokens, gate_w, w0, w1, tok_bf, w0_bf, w1_bf, scales, flags);

  scan_kernel<<<1, 1024, 0, stream>>>(flags, list, counter);

  moe_gemm_sparse<<<GEMM_BLOCKS + ZBLOCKS, 256, 0, stream>>>(
      tok_bf, w0_bf, w1_bf, b0, b1, scales, list, counter, flags, out);
}

// Round 17
// 65.958 us; speedup vs baseline: 1.5584x; 1.0547x over previous
//
#include <hip/hip_runtime.h>
#include <hip/hip_bf16.h>

typedef unsigned short u16;
typedef __bf16 bf16x8 __attribute__((ext_vector_type(8)));
typedef float  f32x4  __attribute__((ext_vector_type(4)));

#define BB    4
#define SS    4096
#define DD    1024
#define EE    8
#define M_TOT (BB*SS)   /* 16384 */
#define N_TOT DD        /* 1024  */
#define K_TOT DD        /* 1024  */

#define BK 64
#define NT (K_TOT/BK)   /* 16 K-tiles */

#define GATE_BLOCKS 1024   /* 16 tokens per block, 4 per wave */
#define BMS 128            /* sparse GEMM M tile */
#define BNS 64             /* sparse GEMM N tile (r16: 128 -> 64 for 2 blocks/CU) */
#define GEMM_BLOCKS ((M_TOT/BMS)*(N_TOT/BNS))  /* 2048 worst-case */
#define ZTOK 32
#define ZBLOCKS (M_TOT/ZTOK)                    /* 512 zero-role blocks */

__device__ __forceinline__ u16 f2bf(float f) {
  unsigned u = __builtin_bit_cast(unsigned, f);
  u += 0x7fffu + ((u >> 16) & 1u);          // round-to-nearest-even
  return (u16)(u >> 16);
}

__device__ __forceinline__ void stage16(u16* lds, const u16* g) {
  __builtin_amdgcn_global_load_lds((const __attribute__((address_space(1))) void*)g,
                                   (__attribute__((address_space(3))) void*)lds,
                                   16, 0, 0);
}

// ---------------------------------------------------------------------------
// Kernel 1: gate (fp32, exact) + token f32->bf16 convert + weight convert.
// Atomic-free (r15 lesson): per-token activity flag only.
// ---------------------------------------------------------------------------
__global__ __launch_bounds__(256) void gate_convert_kernel(
    const float* __restrict__ tokens, const float* __restrict__ gate_w,
    const float* __restrict__ w0,     const float* __restrict__ w1,
    u16* __restrict__ tok_bf, u16* __restrict__ w0_bf, u16* __restrict__ w1_bf,
    float* __restrict__ scales, int* __restrict__ flags)
{
  const int bid = blockIdx.x;
  const int tid = threadIdx.x;

  if (bid < GATE_BLOCKS) {
    __shared__ float gwT[EE][DD];       // 32 KB, transposed gate weights
    #pragma unroll
    for (int r = 0; r < 4; ++r) {
      const int d = r * 256 + tid;      // coalesced: lanes 32B apart
      float4 a = *(const float4*)&gate_w[d * EE];
      float4 b = *(const float4*)&gate_w[d * EE + 4];
      gwT[0][d] = a.x; gwT[1][d] = a.y; gwT[2][d] = a.z; gwT[3][d] = a.w;
      gwT[4][d] = b.x; gwT[5][d] = b.y; gwT[6][d] = b.z; gwT[7][d] = b.w;
    }
    __syncthreads();

    const int lane = tid & 63, wid = tid >> 6;
    const int tbase = (bid * 4 + wid) * 4;          // 4 tokens per wave

    float lg[4][EE];
    #pragma unroll
    for (int t = 0; t < 4; ++t)
      #pragma unroll
      for (int e = 0; e < EE; ++e) lg[t][e] = 0.0f;

    #pragma unroll
    for (int c = 0; c < 4; ++c) {
      const int d = c * 256 + lane * 4;
      float4 gw[EE];
      #pragma unroll
      for (int e = 0; e < EE; ++e)
        gw[e] = *(const float4*)&gwT[e][d];         // ds_read_b128, lanes 16B apart
      #pragma unroll
      for (int t = 0; t < 4; ++t) {
        const size_t off = (size_t)(tbase + t) * DD + d;
        float4 v = *(const float4*)(tokens + off);
        *(ushort4*)(tok_bf + off) =
            make_ushort4(f2bf(v.x), f2bf(v.y), f2bf(v.z), f2bf(v.w));
        #pragma unroll
        for (int e = 0; e < EE; ++e)
          lg[t][e] = fmaf(v.w, gw[e].w, fmaf(v.z, gw[e].z,
                     fmaf(v.y, gw[e].y, fmaf(v.x, gw[e].x, lg[t][e]))));
      }
    }

    // Expert-splitting butterfly reduce, then shuffle softmax/top-2.
    const int b0 = lane & 1, b1 = (lane >> 1) & 1, b2 = (lane >> 2) & 1;
    const int E  = b0 * 4 + (lane & 2) + b2;

    #pragma unroll
    for (int t = 0; t < 4; ++t) {
      float n0[4], n1[2], rr;
      #pragma unroll
      for (int i = 0; i < 4; ++i) {
        float send = b0 ? lg[t][i] : lg[t][i + 4];
        float keep = b0 ? lg[t][i + 4] : lg[t][i];
        n0[i] = keep + __shfl_xor(send, 1, 64);
      }
      #pragma unroll
      for (int i = 0; i < 2; ++i) {
        float send = b1 ? n0[i] : n0[i + 2];
        float keep = b1 ? n0[i + 2] : n0[i];
        n1[i] = keep + __shfl_xor(send, 2, 64);
      }
      {
        float send = b2 ? n1[0] : n1[1];
        float keep = b2 ? n1[1] : n1[0];
        rr = keep + __shfl_xor(send, 4, 64);
      }
      rr += __shfl_xor(rr, 8, 64);
      rr += __shfl_xor(rr, 16, 64);
      rr += __shfl_xor(rr, 32, 64);

      float m = rr;
      m = fmaxf(m, __shfl_xor(m, 1, 64));
      m = fmaxf(m, __shfl_xor(m, 2, 64));
      m = fmaxf(m, __shfl_xor(m, 4, 64));
      float p = __expf(rr - m);
      float s = p;
      s += __shfl_xor(s, 1, 64);
      s += __shfl_xor(s, 2, 64);
      s += __shfl_xor(s, 4, 64);

      int cnt = 0;
      #pragma unroll
      for (int k = 1; k < 8; ++k) {
        float Lo = __shfl_xor(rr, k, 64);
        const int Eo = E ^ ((k & 1) * 4 + (k & 2) + ((k >> 2) & 1));
        cnt += (Lo > rr || (Lo == rr && Eo < E)) ? 1 : 0;
      }
      // lane 4 holds E==1: grab its (cnt==1) predicate.
      const int act1 = __shfl(((E == 1) && (cnt == 1)) ? 1 : 0, 4, 64);
      if (lane < 8) {
        const float w = p / s;
        if (E == 0) scales[(tbase + t) * 2 + 0] = (cnt == 0) ? w : 0.0f;
        if (E == 1) scales[(tbase + t) * 2 + 1] = (cnt == 1) ? w : 0.0f;
      }
      if (lane == 0)
        flags[tbase + t] = ((cnt == 0) ? 1 : 0) | act1;
    }
  } else {
    const int wb = bid - GATE_BLOCKS;            // 0..2047
    const float* src = (wb < 1024) ? w0 : w1;
    u16*        dst = (wb < 1024) ? w0_bf : w1_bf;
    const int base = (wb & 1023) * 1024 + tid * 4;
    float4 v = *(const float4*)(src + base);
    *(ushort4*)(dst + base) =
        make_ushort4(f2bf(v.x), f2bf(v.y), f2bf(v.z), f2bf(v.w));
  }
}

// ---------------------------------------------------------------------------
// Kernel 1.5: single-block prefix-scan list build (deterministic, atomic-free,
// produces a SORTED dense active list + count).  1024 threads x 16 tokens.
// ---------------------------------------------------------------------------
__global__ __launch_bounds__(1024) void scan_kernel(
    const int* __restrict__ flags, int* __restrict__ list,
    int* __restrict__ counter)
{
  __shared__ int wsum[16];
  const int t = threadIdx.x;
  const int lane = t & 63, w = t >> 6;

  int f[16]; int cnt = 0;
  #pragma unroll
  for (int i = 0; i < 16; ++i) { f[i] = flags[t * 16 + i]; cnt += f[i]; }

  // inclusive scan across the wave
  int sc = cnt;
  #pragma unroll
  for (int off = 1; off < 64; off <<= 1) {
    const int v = __shfl_up(sc, off, 64);
    if (lane >= off) sc += v;
  }
  if (lane == 63) wsum[w] = sc;
  __syncthreads();

  if (w == 0) {              // scan the 16 wave totals in wave 0
    int v = (lane < 16) ? wsum[lane] : 0;
    #pragma unroll
    for (int off = 1; off < 16; off <<= 1) {
      const int u = __shfl_up(v, off, 64);
      if (lane >= off) v += u;
    }
    if (lane < 16) wsum[lane] = v;       // inclusive wave prefix
    if (lane == 15) *counter = v;        // total active
  }
  __syncthreads();

  const int wbase = (w == 0) ? 0 : wsum[w - 1];
  int run = wbase + (sc - cnt);          // exclusive prefix for this thread
  #pragma unroll
  for (int i = 0; i < 16; ++i)
    if (f[i]) list[run++] = t * 16 + i;
}

// ---------------------------------------------------------------------------
// Kernel 2: SPARSE fused dual-GEMM over the active-token list (~23% of rows)
// + zero-role blocks streaming zero rows for inactive tokens.
// r16 lesson: 96KB LDS -> 1 block/CU -> 1 wave/SIMD -> fully exposed convoy
// (MfmaUtil 14%, occupancy 8%).  Reshape BN 128->64: LDS 64KB, 2 blocks/CU
// (launch_bounds(256,2)), 480 compute blocks -> independent-block overlap
// (m114) hides the per-block convoy without any schedule change.
// ---------------------------------------------------------------------------
__global__ __launch_bounds__(256, 2) void moe_gemm_sparse(
    const u16* __restrict__ A,    // [M,K] bf16 (token-major)
    const u16* __restrict__ Bw0,  // [N,K] bf16
    const u16* __restrict__ Bw1,  // [N,K] bf16
    const float* __restrict__ bias0, const float* __restrict__ bias1,
    const float* __restrict__ scales, // [M,2]
    const int* __restrict__ list, const int* __restrict__ counter,
    const int* __restrict__ flags,
    float* __restrict__ out)      // [M,N] f32
{
  const int bid = blockIdx.x;
  const int tid = threadIdx.x;

  if (bid >= GEMM_BLOCKS) {
    // ---- zero-role block: 32 tokens, write 4KB zero row if inactive ----
    const int t0 = (bid - GEMM_BLOCKS) * ZTOK;
    const float4 z = make_float4(0.f, 0.f, 0.f, 0.f);
    for (int t = 0; t < ZTOK; ++t) {
      const int tok = t0 + t;
      if (flags[tok] == 0)
        *(float4*)(out + (size_t)tok * DD + tid * 4) = z;
    }
    return;
  }

  const int n_active = *counter;
  const int bm = bid >> 4, bn = bid & 15;      // bn fastest: share A panel in L2
  const int m0 = bm * BMS, n0 = bn * BNS;
  if (m0 >= n_active) return;

  __shared__ u16 lA [2][BMS * BK];   // 32 KiB
  __shared__ u16 lB0[2][BNS * BK];   // 16 KiB
  __shared__ u16 lB1[2][BNS * BK];   // 16 KiB -> 64 KiB total

  const int lane = tid & 63;
  const int wid  = tid >> 6;                  // 0..3
  const int wm = wid >> 1, wn = wid & 1;      // 2M x 2N wave grid (64x32/wave)
  const int fr = lane & 15, fq = lane >> 4;
  const int frh = fr >> 1;                    // read-swizzle term

  // staging: thread covers rows {tid>>3 (+32 per chunk c)}, phys chunk tid&7.
  const int schunk = ((tid & 7) ^ ((tid >> 4) & 7)) * 8;
  const u16* gAr[4];
  #pragma unroll
  for (int c = 0; c < 4; ++c) {
    int m = m0 + (tid >> 3) + 32 * c;
    if (m >= n_active) m = n_active - 1;      // pad: duplicate last row
    gAr[c] = A + (size_t)list[m] * K_TOT + schunk;
  }
  const u16* gB0 = Bw0 + (size_t)(n0 + (tid >> 3)) * K_TOT + schunk;
  const u16* gB1 = Bw1 + (size_t)(n0 + (tid >> 3)) * K_TOT + schunk;

#define STAGE_A(buf, c, ko)  stage16(&lA [buf][(c)*2048 + tid*8], gAr[c] + (ko))
#define STAGE_B0(buf, c, ko) stage16(&lB0[buf][(c)*2048 + tid*8], gB0 + (size_t)(c)*32*K_TOT + (ko))
#define STAGE_B1(buf, c, ko) stage16(&lB1[buf][(c)*2048 + tid*8], gB1 + (size_t)(c)*32*K_TOT + (ko))

#define FRAG(L, buf, rowbase, kk) \
  (*(const bf16x8*)&L[buf][((rowbase) + fr) * BK + ((((kk) << 2) | fq) ^ frh) * 8])

#define BAR()        __builtin_amdgcn_s_barrier()
#define WAIT_VM(N)   asm volatile("s_waitcnt vmcnt(" #N ")" ::: "memory")
#define SGB(m, n)    __builtin_amdgcn_sched_group_barrier((m), (n), 0)

#define MFMA8(ACC, AF, BF) do {                                               \
    __builtin_amdgcn_s_setprio(1);                                            \
    _Pragma("unroll")                                                         \
    for (int i = 0; i < 4; ++i)                                               \
      _Pragma("unroll")                                                       \
      for (int j = 0; j < 2; ++j)                                             \
        ACC[i][j] = __builtin_amdgcn_mfma_f32_16x16x32_bf16(AF[i], BF[j],     \
                                                            ACC[i][j], 0,0,0);\
    __builtin_amdgcn_s_setprio(0);                                            \
  } while (0)

#define STAGE_ALL(buf, ko) do {                                               \
    STAGE_A(buf, 0, ko);  STAGE_A(buf, 1, ko);                                \
    STAGE_A(buf, 2, ko);  STAGE_A(buf, 3, ko);                                \
    STAGE_B0(buf, 0, ko); STAGE_B0(buf, 1, ko);                               \
    STAGE_B1(buf, 0, ko); STAGE_B1(buf, 1, ko);                               \
  } while (0)

  f32x4 acc0[4][2] = {};
  f32x4 acc1[4][2] = {};
  bf16x8 afA[4], afB[4], b0A[2], b0B[2], b1A[2], b1B[2];

  // Prologue: stage K-tile 0, drain, barrier.
  STAGE_ALL(0, 0);
  WAIT_VM(0);
  BAR();

  int cur = 0;
  for (int t = 0; t < NT - 1; ++t) {
    const int nxt = cur ^ 1;
    const size_t ko = (size_t)(t + 1) * BK;

    // reads: q1(afA,b0A) q2(afB,b0B) q3(b1A,b1B)
    #pragma unroll
    for (int i = 0; i < 4; ++i) afA[i] = FRAG(lA,  cur, wm * 64 + i * 16, 0);
    #pragma unroll
    for (int j = 0; j < 2; ++j) b0A[j] = FRAG(lB0, cur, wn * 32 + j * 16, 0);
    #pragma unroll
    for (int i = 0; i < 4; ++i) afB[i] = FRAG(lA,  cur, wm * 64 + i * 16, 1);
    #pragma unroll
    for (int j = 0; j < 2; ++j) b0B[j] = FRAG(lB0, cur, wn * 32 + j * 16, 1);
    #pragma unroll
    for (int j = 0; j < 2; ++j) b1A[j] = FRAG(lB1, cur, wn * 32 + j * 16, 0);
    #pragma unroll
    for (int j = 0; j < 2; ++j) b1B[j] = FRAG(lB1, cur, wn * 32 + j * 16, 1);
    STAGE_ALL(nxt, ko);

    MFMA8(acc0, afA, b0A);
    MFMA8(acc0, afB, b0B);
    MFMA8(acc1, afA, b1A);
    MFMA8(acc1, afB, b1B);

    // interleave pins: batch1 after q1; stages+q2/q3 drain under batches.
    SGB(0x100, 6);  SGB(0x008, 8);
    SGB(0x100, 6);  SGB(0x010, 4);  SGB(0x008, 8);
    SGB(0x100, 4);  SGB(0x010, 4);  SGB(0x008, 8);
    SGB(0x008, 8);

    WAIT_VM(0);
    BAR();
    cur = nxt;
  }

  // Peeled last tile (no prefetch).
  {
    #pragma unroll
    for (int i = 0; i < 4; ++i) afA[i] = FRAG(lA,  cur, wm * 64 + i * 16, 0);
    #pragma unroll
    for (int j = 0; j < 2; ++j) b0A[j] = FRAG(lB0, cur, wn * 32 + j * 16, 0);
    #pragma unroll
    for (int i = 0; i < 4; ++i) afB[i] = FRAG(lA,  cur, wm * 64 + i * 16, 1);
    #pragma unroll
    for (int j = 0; j < 2; ++j) b0B[j] = FRAG(lB0, cur, wn * 32 + j * 16, 1);
    #pragma unroll
    for (int j = 0; j < 2; ++j) b1A[j] = FRAG(lB1, cur, wn * 32 + j * 16, 0);
    #pragma unroll
    for (int j = 0; j < 2; ++j) b1B[j] = FRAG(lB1, cur, wn * 32 + j * 16, 1);
    MFMA8(acc0, afA, b0A);
    MFMA8(acc0, afB, b0B);
    MFMA8(acc1, afA, b1A);
    MFMA8(acc1, afB, b1B);
  }

  // Epilogue: scatter out[list[m]] = s0*silu(acc0+b0) + s1*silu(acc1+b1)
  float bb0[2], bb1[2];
  #pragma unroll
  for (int j = 0; j < 2; ++j) {
    const int col = n0 + wn * 32 + j * 16 + fr;
    bb0[j] = bias0[col];
    bb1[j] = bias1[col];
  }
  #pragma unroll
  for (int i = 0; i < 4; ++i) {
    #pragma unroll
    for (int r = 0; r < 4; ++r) {
      const int m = m0 + wm * 64 + i * 16 + fq * 4 + r;  // C row=(lane>>4)*4+reg
      if (m < n_active) {
        const int gidx = list[m];
        const float s0 = scales[gidx * 2 + 0];
        const float s1 = scales[gidx * 2 + 1];
        float* orow = out + (size_t)gidx * N_TOT + n0 + wn * 32;
        #pragma unroll
        for (int j = 0; j < 2; ++j) {
          const float v0 = acc0[i][j][r] + bb0[j];
          const float v1 = acc1[i][j][r] + bb1[j];
          const float g0 = v0 / (1.0f + __expf(-v0));
          const float g1 = v1 / (1.0f + __expf(-v1));
          orow[j * 16 + fr] = s0 * g0 + s1 * g1;           // col = lane&15
        }
      }
    }
  }
#undef STAGE_A
#undef STAGE_B0
#undef STAGE_B1
#undef STAGE_ALL
#undef FRAG
#undef BAR
#undef WAIT_VM
#undef SGB
#undef MFMA8
}

// ---------------------------------------------------------------------------
extern "C" void kernel_launch(void* const* d_in, const int* in_sizes, int n_in,
                              void* d_out, int out_size, void* d_ws, size_t ws_size,
                              hipStream_t stream)
{
  const float* tokens = (const float*)d_in[0];
  const float* gate_w = (const float*)d_in[1];
  const float* w0     = (const float*)d_in[2];
  const float* b0     = (const float*)d_in[3];
  const float* w1     = (const float*)d_in[4];
  const float* b1     = (const float*)d_in[5];
  float* out = (float*)d_out;

  char* ws = (char*)d_ws;
  const size_t off_w0  = (size_t)M_TOT * K_TOT * 2;            // 32 MB
  const size_t off_w1  = off_w0 + (size_t)N_TOT * K_TOT * 2;   // +2 MB
  const size_t off_sc  = off_w1 + (size_t)N_TOT * K_TOT * 2;   // +2 MB
  const size_t off_cnt = off_sc + (size_t)M_TOT * 2 * 4;       // +128 KB
  const size_t off_lst = off_cnt + 256;
  const size_t off_flg = off_lst + (size_t)M_TOT * 4;          // +64 KB

  u16* tok_bf   = (u16*)ws;
  u16* w0_bf    = (u16*)(ws + off_w0);
  u16* w1_bf    = (u16*)(ws + off_w1);
  float* scales = (float*)(ws + off_sc);
  int* counter  = (int*)(ws + off_cnt);
  int* list     = (int*)(ws + off_lst);
  int* flags    = (int*)(ws + off_flg);

  gate_convert_kernel<<<GATE_BLOCKS + 2048, 256, 0, stream>>>(
      tokens, gate_w, w0, w1, tok_bf, w0_bf, w1_bf, scales, flags);

  scan_kernel<<<1, 1024, 0, stream>>>(flags, list, counter);

  moe_gemm_sparse<<<GEMM_BLOCKS + ZBLOCKS, 256, 0, stream>>>(
      tok_bf, w0_bf, w1_bf, b0, b1, scales, list, counter, flags, out);
}